// Round 4
// baseline (29.003 us; speedup 1.0000x reference)
//
#include <hip/hip_runtime.h>

// mIoU loss: mean over B pairs of (1 - IoU(output[i], target[i])).
// Inputs: d_in[0] = output [B,4] f32, d_in[1] = target [B,4] f32.
// Output: d_out[0] = scalar f32.
//
// Memory-bound streaming reduction: 32 B/pair, 128 MB total @ B=4M.
// R3: grid 1024->2048 blocks (fills all 8192 wave slots; was grid-limited
// at 36.9% occupancy) + 4x manual unroll so each thread holds 8
// global_load_dwordx4 in flight (ILP for latency hiding).
// Two-pass deterministic reduction (no float atomics -> bitwise stable
// across graph replays): pass 1 writes one f32 partial per block to d_ws,
// pass 2 sums partials in double and writes the mean.

#define BLOCK 256
#define NBLOCKS 2048  // 2048*256 = 524288 threads = 8192 waves = 32/CU

__device__ __forceinline__ float iou_loss(float4 a, float4 b) {
    float lt_x = fmaxf(a.x, b.x);
    float lt_y = fmaxf(a.y, b.y);
    float rb_x = fminf(a.z, b.z);
    float rb_y = fminf(a.w, b.w);

    float w = fmaxf(rb_x - lt_x, 0.0f);
    float h = fmaxf(rb_y - lt_y, 0.0f);
    float inter = w * h;

    float areaA = (a.z - a.x) * (a.w - a.y);
    float areaB = (b.z - b.x) * (b.w - b.y);
    float uni = areaA + areaB - inter;  // > 0: boxes have wh >= 1

    return 1.0f - inter / uni;
}

__global__ __launch_bounds__(BLOCK) void miou_partial(
    const float4* __restrict__ boxA,   // output boxes, one float4 each
    const float4* __restrict__ boxB,   // target boxes
    float* __restrict__ partials,      // [gridDim.x]
    int n)                             // number of pairs
{
    int tid = blockIdx.x * BLOCK + threadIdx.x;
    int stride = gridDim.x * BLOCK;

    float acc = 0.0f;
    int i = tid;

    // main loop: 4 pairs/thread/iter, 8 loads issued before any consume
    for (; i + 3 * stride < n; i += 4 * stride) {
        float4 a0 = boxA[i];
        float4 a1 = boxA[i + stride];
        float4 a2 = boxA[i + 2 * stride];
        float4 a3 = boxA[i + 3 * stride];
        float4 b0 = boxB[i];
        float4 b1 = boxB[i + stride];
        float4 b2 = boxB[i + 2 * stride];
        float4 b3 = boxB[i + 3 * stride];
        acc += iou_loss(a0, b0);
        acc += iou_loss(a1, b1);
        acc += iou_loss(a2, b2);
        acc += iou_loss(a3, b3);
    }
    // tail
    for (; i < n; i += stride)
        acc += iou_loss(boxA[i], boxB[i]);

    // wave (64-lane) shuffle reduction
    #pragma unroll
    for (int off = 32; off > 0; off >>= 1)
        acc += __shfl_down(acc, off, 64);

    __shared__ float s[BLOCK / 64];
    int lane = threadIdx.x & 63;
    int wid  = threadIdx.x >> 6;
    if (lane == 0) s[wid] = acc;
    __syncthreads();

    if (threadIdx.x == 0) {
        float t = 0.0f;
        #pragma unroll
        for (int w2 = 0; w2 < BLOCK / 64; ++w2) t += s[w2];
        partials[blockIdx.x] = t;  // fully rewritten every call
    }
}

__global__ __launch_bounds__(BLOCK) void miou_final(
    const float* __restrict__ partials, int np,
    float* __restrict__ out, int n)
{
    double acc = 0.0;
    for (int i = threadIdx.x; i < np; i += BLOCK)
        acc += (double)partials[i];

    #pragma unroll
    for (int off = 32; off > 0; off >>= 1)
        acc += __shfl_down(acc, off, 64);

    __shared__ double s[BLOCK / 64];
    int lane = threadIdx.x & 63;
    int wid  = threadIdx.x >> 6;
    if (lane == 0) s[wid] = acc;
    __syncthreads();

    if (threadIdx.x == 0) {
        double t = 0.0;
        #pragma unroll
        for (int w2 = 0; w2 < BLOCK / 64; ++w2) t += s[w2];
        out[0] = (float)(t / (double)n);  // unconditional overwrite of d_out
    }
}

extern "C" void kernel_launch(void* const* d_in, const int* in_sizes, int n_in,
                              void* d_out, int out_size, void* d_ws, size_t ws_size,
                              hipStream_t stream) {
    const float4* boxA = (const float4*)d_in[0];  // output [B,4] f32
    const float4* boxB = (const float4*)d_in[1];  // target [B,4] f32
    int n = in_sizes[0] / 4;                      // number of box pairs

    float* partials = (float*)d_ws;               // NBLOCKS * 4 B = 8 KB scratch
    float* out = (float*)d_out;

    miou_partial<<<NBLOCKS, BLOCK, 0, stream>>>(boxA, boxB, partials, n);
    miou_final<<<1, BLOCK, 0, stream>>>(partials, NBLOCKS, out, n);
}

// Round 5
// 25.263 us; speedup vs baseline: 1.1481x; 1.1481x over previous
//
#include <hip/hip_runtime.h>

// mIoU loss: mean over B pairs of (1 - IoU(output[i], target[i])).
// Inputs: d_in[0] = output [B,4] f32, d_in[1] = target [B,4] f32.
// Output: d_out[0] = scalar f32.
//
// Memory-bound streaming reduction: 32 B/pair, 128 MB total @ B=4M.
// R4 findings: doubling waves (R3) left kernel time unchanged -> main
// kernel is path-BW-bound (~5.8 TB/s effective warm), not latency-bound.
// So: revert main kernel to the lean R2 structure (1024 blocks, 12 VGPR),
// and attack the fixed tail instead: final reduce is now a single wave
// (64 threads), float4 loads, shuffle-only reduce - no LDS, no barriers.
// Two-pass deterministic reduction (no float atomics -> bitwise stable
// across graph replays).

#define BLOCK 256
#define NBLOCKS 1024   // partials buffer = 4 KB in d_ws

__global__ __launch_bounds__(BLOCK) void miou_partial(
    const float4* __restrict__ boxA,   // output boxes, one float4 each
    const float4* __restrict__ boxB,   // target boxes
    float* __restrict__ partials,      // [NBLOCKS]
    int n)                             // number of pairs
{
    int tid = blockIdx.x * BLOCK + threadIdx.x;
    int stride = gridDim.x * BLOCK;

    float acc = 0.0f;
    for (int i = tid; i < n; i += stride) {
        float4 a = boxA[i];  // (x1, y1, x2, y2)
        float4 b = boxB[i];

        float lt_x = fmaxf(a.x, b.x);
        float lt_y = fmaxf(a.y, b.y);
        float rb_x = fminf(a.z, b.z);
        float rb_y = fminf(a.w, b.w);

        float w = fmaxf(rb_x - lt_x, 0.0f);
        float h = fmaxf(rb_y - lt_y, 0.0f);
        float inter = w * h;

        float areaA = (a.z - a.x) * (a.w - a.y);
        float areaB = (b.z - b.x) * (b.w - b.y);
        float uni = areaA + areaB - inter;  // > 0: boxes have wh >= 1

        acc += 1.0f - inter / uni;
    }

    // wave (64-lane) shuffle reduction
    #pragma unroll
    for (int off = 32; off > 0; off >>= 1)
        acc += __shfl_down(acc, off, 64);

    __shared__ float s[BLOCK / 64];
    int lane = threadIdx.x & 63;
    int wid  = threadIdx.x >> 6;
    if (lane == 0) s[wid] = acc;
    __syncthreads();

    if (threadIdx.x == 0) {
        float t = 0.0f;
        #pragma unroll
        for (int w2 = 0; w2 < BLOCK / 64; ++w2) t += s[w2];
        partials[blockIdx.x] = t;  // fully rewritten every call
    }
}

// Single-wave final reduce: 1024 partials = 256 float4, 4 per lane.
// No LDS, no __syncthreads - pure shuffle. Sums in double for accuracy.
__global__ __launch_bounds__(64) void miou_final(
    const float4* __restrict__ partials4,  // [NBLOCKS/4]
    float* __restrict__ out, int n)
{
    int lane = threadIdx.x;  // 0..63

    double acc = 0.0;
    #pragma unroll
    for (int j = 0; j < NBLOCKS / 4 / 64; ++j) {   // 4 float4 per lane
        float4 p = partials4[lane + j * 64];
        acc += (double)p.x + (double)p.y + (double)p.z + (double)p.w;
    }

    #pragma unroll
    for (int off = 32; off > 0; off >>= 1)
        acc += __shfl_down(acc, off, 64);

    if (lane == 0)
        out[0] = (float)(acc / (double)n);  // unconditional overwrite of d_out
}

extern "C" void kernel_launch(void* const* d_in, const int* in_sizes, int n_in,
                              void* d_out, int out_size, void* d_ws, size_t ws_size,
                              hipStream_t stream) {
    const float4* boxA = (const float4*)d_in[0];  // output [B,4] f32
    const float4* boxB = (const float4*)d_in[1];  // target [B,4] f32
    int n = in_sizes[0] / 4;                      // number of box pairs

    float* partials = (float*)d_ws;               // NBLOCKS * 4 B = 4 KB scratch
    float* out = (float*)d_out;

    miou_partial<<<NBLOCKS, BLOCK, 0, stream>>>(boxA, boxB, partials, n);
    miou_final<<<1, 64, 0, stream>>>((const float4*)partials, out, n);
}